// Round 1
// baseline (1901.680 us; speedup 1.0000x reference)
//
#include <hip/hip_runtime.h>

#define BATCH 512
#define TMAX 1024
#define DIN 4
#define H 64
#define NC 1098

__device__ __forceinline__ float sigmoidf_(float x) {
    return 1.0f / (1.0f + __expf(-x));
}
__device__ __forceinline__ float tanhf_(float x) {
    // tanh(x) = 1 - 2/(e^{2x}+1); saturates correctly at +-inf
    return 1.0f - 2.0f / (__expf(2.0f * x) + 1.0f);
}

// ---------------- Layer 0 (bidirectional), one block per (sequence, dir) ----
// Thread g in [0,256) owns gate row g. Weights in registers, h/c in LDS.
// x[b] (<=16KB) staged entirely in LDS so the recurrence loop touches no HBM
// except the h0 store.
__global__ __launch_bounds__(256) void lstm_layer0(
    const float* __restrict__ x, const int* __restrict__ lengths,
    const float* __restrict__ Wih_f, const float* __restrict__ Whh_f,
    const float* __restrict__ bih_f, const float* __restrict__ bhh_f,
    const float* __restrict__ Wih_b, const float* __restrict__ Whh_b,
    const float* __restrict__ bih_b, const float* __restrict__ bhh_b,
    float* __restrict__ h0 /* [B, T, 2H] */)
{
    const int b   = blockIdx.x;
    const int dir = blockIdx.y;
    const int g   = threadIdx.x;
    const int L   = lengths[b];

    const float* Wih = dir ? Wih_b : Wih_f;
    const float* Whh = dir ? Whh_b : Whh_f;
    const float* bih = dir ? bih_b : bih_f;
    const float* bhh = dir ? bhh_b : bhh_f;

    // per-thread weight row
    float whh[H];
    {
        const float4* wv = (const float4*)(Whh + g * H);
        #pragma unroll
        for (int k = 0; k < H / 4; k++) {
            float4 v = wv[k];
            whh[4*k+0] = v.x; whh[4*k+1] = v.y; whh[4*k+2] = v.z; whh[4*k+3] = v.w;
        }
    }
    const float4 wih = *(const float4*)(Wih + g * DIN);
    const float bias = bih[g] + bhh[g];

    __shared__ __align__(16) float xbuf[TMAX * DIN]; // 16 KB
    __shared__ __align__(16) float h_s[H];
    __shared__ __align__(16) float c_s[H];
    __shared__ float gates[256];

    // stage x[b, 0:L, :] into LDS (coalesced)
    const int nx = L * DIN;
    for (int i = g; i < nx; i += 256)
        xbuf[i] = x[(size_t)b * (TMAX * DIN) + i];

    if (g < H) { h_s[g] = 0.0f; c_s[g] = 0.0f; }
    __syncthreads();

    for (int s = 0; s < L; s++) {
        const int t = dir ? (L - 1 - s) : s;  // packed-seq reversal within L
        const float4 xt = *(const float4*)(xbuf + t * DIN);

        float acc = bias;
        acc = fmaf(wih.x, xt.x, acc);
        acc = fmaf(wih.y, xt.y, acc);
        acc = fmaf(wih.z, xt.z, acc);
        acc = fmaf(wih.w, xt.w, acc);
        const float4* h4 = (const float4*)h_s;
        #pragma unroll
        for (int k = 0; k < H / 4; k++) {
            float4 hv = h4[k];
            acc = fmaf(whh[4*k+0], hv.x, acc);
            acc = fmaf(whh[4*k+1], hv.y, acc);
            acc = fmaf(whh[4*k+2], hv.z, acc);
            acc = fmaf(whh[4*k+3], hv.w, acc);
        }
        // PyTorch gate order: i(0:64) f(64:128) g(128:192) o(192:256)
        gates[g] = (g >= 128 && g < 192) ? tanhf_(acc) : sigmoidf_(acc);
        __syncthreads();
        if (g < H) {
            const float ig = gates[g], fg = gates[H + g];
            const float gg = gates[2*H + g], og = gates[3*H + g];
            const float c = fmaf(fg, c_s[g], ig * gg);
            const float h = og * tanhf_(c);
            c_s[g] = c; h_s[g] = h;
            h0[((size_t)b * TMAX + t) * (2*H) + dir * H + g] = h;
        }
        __syncthreads();
    }
}

// ---------------- Layer 1 forward + single backward step + logits -----------
// One block per sequence. Forward scan over t=0..L-1 with 1-step register
// prefetch of h0 rows. The gather point only needs the backward direction's
// FIRST step (zero state -> W_hh_l1b unused). Logits fused at the end.
__global__ __launch_bounds__(256, 1) void lstm_layer1(
    const float* __restrict__ h0, const int* __restrict__ lengths,
    const float* __restrict__ Wih_f, const float* __restrict__ Whh_f,
    const float* __restrict__ bih_f, const float* __restrict__ bhh_f,
    const float* __restrict__ Wih_b,
    const float* __restrict__ bih_b, const float* __restrict__ bhh_b,
    const float* __restrict__ Wout, const float* __restrict__ bout,
    float* __restrict__ out)
{
    const int b = blockIdx.x;
    const int g = threadIdx.x;
    const int L = lengths[b];

    float wih[2*H];
    {
        const float4* wv = (const float4*)(Wih_f + g * (2*H));
        #pragma unroll
        for (int k = 0; k < (2*H) / 4; k++) {
            float4 v = wv[k];
            wih[4*k+0] = v.x; wih[4*k+1] = v.y; wih[4*k+2] = v.z; wih[4*k+3] = v.w;
        }
    }
    float whh[H];
    {
        const float4* wv = (const float4*)(Whh_f + g * H);
        #pragma unroll
        for (int k = 0; k < H / 4; k++) {
            float4 v = wv[k];
            whh[4*k+0] = v.x; whh[4*k+1] = v.y; whh[4*k+2] = v.z; whh[4*k+3] = v.w;
        }
    }
    const float bias = bih_f[g] + bhh_f[g];

    __shared__ __align__(16) float xs[2*H];
    __shared__ __align__(16) float h_s[H];
    __shared__ __align__(16) float c_s[H];
    __shared__ float gates[256];
    __shared__ __align__(16) float yvec[2*H];

    if (g < H) { h_s[g] = 0.0f; c_s[g] = 0.0f; }
    float pre = 0.0f;
    if (g < 2*H) {
        pre = h0[((size_t)b * TMAX + 0) * (2*H) + g];
        xs[g] = pre;
    }
    __syncthreads();

    for (int s = 0; s < L; s++) {
        // prefetch next input row into a register (latency hidden by compute)
        if (g < 2*H && s + 1 < L)
            pre = h0[((size_t)b * TMAX + (s + 1)) * (2*H) + g];

        float acc = bias;
        const float4* xv = (const float4*)xs;
        #pragma unroll
        for (int k = 0; k < (2*H) / 4; k++) {
            float4 v = xv[k];
            acc = fmaf(wih[4*k+0], v.x, acc);
            acc = fmaf(wih[4*k+1], v.y, acc);
            acc = fmaf(wih[4*k+2], v.z, acc);
            acc = fmaf(wih[4*k+3], v.w, acc);
        }
        const float4* h4 = (const float4*)h_s;
        #pragma unroll
        for (int k = 0; k < H / 4; k++) {
            float4 hv = h4[k];
            acc = fmaf(whh[4*k+0], hv.x, acc);
            acc = fmaf(whh[4*k+1], hv.y, acc);
            acc = fmaf(whh[4*k+2], hv.z, acc);
            acc = fmaf(whh[4*k+3], hv.w, acc);
        }
        gates[g] = (g >= 128 && g < 192) ? tanhf_(acc) : sigmoidf_(acc);
        __syncthreads();
        if (g < H) {
            const float ig = gates[g], fg = gates[H + g];
            const float gg = gates[2*H + g], og = gates[3*H + g];
            const float c = fmaf(fg, c_s[g], ig * gg);
            c_s[g] = c;
            h_s[g] = og * tanhf_(c);
        }
        if (g < 2*H) xs[g] = pre;  // xs now holds row for step s+1 (or stays = row L-1)
        __syncthreads();
    }
    // h_s = h1_forward at t=L-1; xs = h0[b, L-1, :] (invariant from the loop)
    if (g < H) yvec[g] = h_s[g];

    // backward direction, first step only, zero state => no W_hh term
    {
        const float4* wv = (const float4*)(Wih_b + g * (2*H));
        #pragma unroll
        for (int k = 0; k < (2*H) / 4; k++) {
            float4 v = wv[k];
            wih[4*k+0] = v.x; wih[4*k+1] = v.y; wih[4*k+2] = v.z; wih[4*k+3] = v.w;
        }
    }
    float accb = bih_b[g] + bhh_b[g];
    {
        const float4* xv = (const float4*)xs;
        #pragma unroll
        for (int k = 0; k < (2*H) / 4; k++) {
            float4 v = xv[k];
            accb = fmaf(wih[4*k+0], v.x, accb);
            accb = fmaf(wih[4*k+1], v.y, accb);
            accb = fmaf(wih[4*k+2], v.z, accb);
            accb = fmaf(wih[4*k+3], v.w, accb);
        }
    }
    gates[g] = (g >= 128 && g < 192) ? tanhf_(accb) : sigmoidf_(accb);
    __syncthreads();
    if (g < H) {
        const float ig = gates[g];
        const float gg = gates[2*H + g], og = gates[3*H + g];
        const float c = ig * gg;               // c_prev = 0
        yvec[H + g] = og * tanhf_(c);
    }
    __syncthreads();

    // logits: out[b, :] = [h1f_last, h1b_first] @ Wout^T + bout
    const float4* yv = (const float4*)yvec;
    for (int o = g; o < NC; o += 256) {
        float acc2 = bout[o];
        const float4* wr = (const float4*)(Wout + (size_t)o * (2*H));
        #pragma unroll
        for (int k = 0; k < (2*H) / 4; k++) {
            float4 w = wr[k];
            float4 y = yv[k];
            acc2 = fmaf(w.x, y.x, acc2);
            acc2 = fmaf(w.y, y.y, acc2);
            acc2 = fmaf(w.z, y.z, acc2);
            acc2 = fmaf(w.w, y.w, acc2);
        }
        out[(size_t)b * NC + o] = acc2;
    }
}

extern "C" void kernel_launch(void* const* d_in, const int* in_sizes, int n_in,
                              void* d_out, int out_size, void* d_ws, size_t ws_size,
                              hipStream_t stream) {
    const float* x        = (const float*)d_in[0];
    const int*   lengths  = (const int*)  d_in[1];
    const float* Wih_l0f  = (const float*)d_in[2];
    const float* Whh_l0f  = (const float*)d_in[3];
    const float* bih_l0f  = (const float*)d_in[4];
    const float* bhh_l0f  = (const float*)d_in[5];
    const float* Wih_l0b  = (const float*)d_in[6];
    const float* Whh_l0b  = (const float*)d_in[7];
    const float* bih_l0b  = (const float*)d_in[8];
    const float* bhh_l0b  = (const float*)d_in[9];
    const float* Wih_l1f  = (const float*)d_in[10];
    const float* Whh_l1f  = (const float*)d_in[11];
    const float* bih_l1f  = (const float*)d_in[12];
    const float* bhh_l1f  = (const float*)d_in[13];
    const float* Wih_l1b  = (const float*)d_in[14];
    // d_in[15] = Whh_l1b: unused (backward dir only needs its first step, h=0)
    const float* bih_l1b  = (const float*)d_in[16];
    const float* bhh_l1b  = (const float*)d_in[17];
    const float* Wout     = (const float*)d_in[18];
    const float* bout     = (const float*)d_in[19];
    float* out = (float*)d_out;

    float* h0 = (float*)d_ws;  // [B, T, 2H] fp32 = 256 MB

    lstm_layer0<<<dim3(BATCH, 2), 256, 0, stream>>>(
        x, lengths,
        Wih_l0f, Whh_l0f, bih_l0f, bhh_l0f,
        Wih_l0b, Whh_l0b, bih_l0b, bhh_l0b, h0);

    lstm_layer1<<<dim3(BATCH), 256, 0, stream>>>(
        h0, lengths,
        Wih_l1f, Whh_l1f, bih_l1f, bhh_l1f,
        Wih_l1b, bih_l1b, bhh_l1b,
        Wout, bout, out);
}

// Round 2
// 1889.289 us; speedup vs baseline: 1.0066x; 1.0066x over previous
//
#include <hip/hip_runtime.h>

#define BATCH 512
#define TMAX 1024
#define DIN 4
#define H 64
#define NC 1098

__device__ __forceinline__ float sigmoidf_(float x) {
    return 1.0f / (1.0f + __expf(-x));
}
__device__ __forceinline__ float tanhf_(float x) {
    return 1.0f - 2.0f / (__expf(2.0f * x) + 1.0f);
}

// ---------------- Layer 0 (bidirectional), one block per (sequence, dir) ----
// 4-way partial accumulators break the fp32 FMA dependency chain (~4cyc dep
// latency; single-acc chain was 272 cyc). h rows buffered in an LDS ring and
// flushed every 64 steps so the compiler's vmcnt(0)-before-s_barrier drain is
// amortized 64x instead of hitting every step.
__global__ __launch_bounds__(256) void lstm_layer0(
    const float* __restrict__ x, const int* __restrict__ lengths,
    const float* __restrict__ Wih_f, const float* __restrict__ Whh_f,
    const float* __restrict__ bih_f, const float* __restrict__ bhh_f,
    const float* __restrict__ Wih_b, const float* __restrict__ Whh_b,
    const float* __restrict__ bih_b, const float* __restrict__ bhh_b,
    float* __restrict__ h0 /* [B, T, 2H] */)
{
    const int b   = blockIdx.x;
    const int dir = blockIdx.y;
    const int g   = threadIdx.x;
    const int L   = lengths[b];

    const float* Wih = dir ? Wih_b : Wih_f;
    const float* Whh = dir ? Whh_b : Whh_f;
    const float bias = dir ? (bih_b[g] + bhh_b[g]) : (bih_f[g] + bhh_f[g]);

    float whh[H];
    {
        const float4* wv = (const float4*)(Whh + g * H);
        #pragma unroll
        for (int k = 0; k < H / 4; k++) {
            float4 v = wv[k];
            whh[4*k+0] = v.x; whh[4*k+1] = v.y; whh[4*k+2] = v.z; whh[4*k+3] = v.w;
        }
    }
    const float4 wih = *(const float4*)(Wih + g * DIN);

    __shared__ __align__(16) float4 xbuf4[TMAX];     // 16 KB: whole x[b]
    __shared__ __align__(16) float hist[64 * H];     // 16 KB: h ring buffer
    __shared__ __align__(16) float h_s[H];
    __shared__ __align__(16) float c_s[H];
    __shared__ float gates[256];

    {
        const float4* x4 = (const float4*)x + (size_t)b * TMAX;
        for (int i = g; i < L; i += 256) xbuf4[i] = x4[i];
    }
    if (g < H) { h_s[g] = 0.0f; c_s[g] = 0.0f; }
    __syncthreads();

    for (int s = 0; s < L; s++) {
        const int t = dir ? (L - 1 - s) : s;
        const float4 xt = xbuf4[t];

        float a0 = bias, a1 = 0.0f, a2 = 0.0f, a3 = 0.0f;
        a0 = fmaf(wih.x, xt.x, a0); a1 = fmaf(wih.y, xt.y, a1);
        a2 = fmaf(wih.z, xt.z, a2); a3 = fmaf(wih.w, xt.w, a3);
        const float4* h4 = (const float4*)h_s;
        #pragma unroll
        for (int k = 0; k < H / 4; k++) {
            float4 hv = h4[k];
            a0 = fmaf(whh[4*k+0], hv.x, a0);
            a1 = fmaf(whh[4*k+1], hv.y, a1);
            a2 = fmaf(whh[4*k+2], hv.z, a2);
            a3 = fmaf(whh[4*k+3], hv.w, a3);
        }
        const float acc = (a0 + a1) + (a2 + a3);
        // waves are gate-aligned: wave2 (g=128..191) is all-tanh, no divergence
        gates[g] = (g >= 128 && g < 192) ? tanhf_(acc) : sigmoidf_(acc);
        __syncthreads();
        if (g < H) {
            const float ig = gates[g], fg = gates[H + g];
            const float gg = gates[2*H + g], og = gates[3*H + g];
            const float c = fmaf(fg, c_s[g], ig * gg);
            const float h = og * tanhf_(c);
            c_s[g] = c; h_s[g] = h;
            hist[(s & 63) * H + g] = h;
        }
        __syncthreads();
        if ((s & 63) == 63 || s == L - 1) {
            // cooperative flush of the chunk; hist slot 0 is only rewritten
            // after the NEXT step's first barrier, which drains these reads.
            const int s0 = s & ~63;
            const int nrows = s - s0 + 1;
            const int cc = g & 15, rb = g >> 4;
            #pragma unroll
            for (int j = 0; j < 4; j++) {
                const int r = rb + 16 * j;
                if (r < nrows) {
                    const int t2 = dir ? (L - 1 - (s0 + r)) : (s0 + r);
                    const float4 hv = *(const float4*)(hist + r * H + cc * 4);
                    *(float4*)(h0 + ((size_t)b * TMAX + t2) * (2*H) + dir * H + cc * 4) = hv;
                }
            }
        }
    }
}

// ---------------- xW GEMM for layer 1 forward: G1 = h0 @ Wih^T + b ----------
// Fully parallel (no recurrence). Tile = 64 rows x 256 cols, K=128. Thread g
// holds Wih row g in regs; X rows broadcast from LDS.
__global__ __launch_bounds__(256) void xw_gemm(
    const float* __restrict__ h0, const int* __restrict__ lengths,
    const float* __restrict__ Wih, const float* __restrict__ bih,
    const float* __restrict__ bhh, float* __restrict__ G1 /* [B, T, 4H] */)
{
    const int b  = blockIdx.y;
    const int t0 = blockIdx.x * 64;
    const int L  = lengths[b];
    if (t0 >= L) return;
    const int V = min(64, L - t0);
    const int g = threadIdx.x;

    float w[2*H];
    {
        const float4* wv = (const float4*)(Wih + g * (2*H));
        #pragma unroll
        for (int k = 0; k < (2*H) / 4; k++) {
            float4 v = wv[k];
            w[4*k+0] = v.x; w[4*k+1] = v.y; w[4*k+2] = v.z; w[4*k+3] = v.w;
        }
    }
    const float bb = bih[g] + bhh[g];

    __shared__ __align__(16) float4 xs4[64 * 32];  // 32 KB
    {
        const float4* src = (const float4*)h0 + ((size_t)b * TMAX + t0) * 32;
        for (int i = g; i < V * 32; i += 256) xs4[i] = src[i];
    }
    __syncthreads();

    for (int r = 0; r < V; r++) {
        const float4* xr = xs4 + r * 32;
        float a0 = bb, a1 = 0.0f, a2 = 0.0f, a3 = 0.0f;
        #pragma unroll
        for (int k = 0; k < 32; k++) {
            float4 v = xr[k];
            a0 = fmaf(w[4*k+0], v.x, a0);
            a1 = fmaf(w[4*k+1], v.y, a1);
            a2 = fmaf(w[4*k+2], v.z, a2);
            a3 = fmaf(w[4*k+3], v.w, a3);
        }
        G1[((size_t)b * TMAX + t0 + r) * (4*H) + g] = (a0 + a1) + (a2 + a3);
    }
}

// ---------------- Layer 1 recurrence (GEMM path): only W_hh @ h per step ----
// G1 chunk-staged into LDS every 64 steps (one vmcnt drain per 64 steps, zero
// per-step global ops). Epilogue: backward-dir first step + logits.
__global__ __launch_bounds__(256) void lstm_layer1_rec(
    const float* __restrict__ G1, const float* __restrict__ h0,
    const int* __restrict__ lengths,
    const float* __restrict__ Whh_f,
    const float* __restrict__ Wih_b,
    const float* __restrict__ bih_b, const float* __restrict__ bhh_b,
    const float* __restrict__ Wout, const float* __restrict__ bout,
    float* __restrict__ out)
{
    const int b = blockIdx.x;
    const int g = threadIdx.x;
    const int L = lengths[b];

    float whh[H];
    {
        const float4* wv = (const float4*)(Whh_f + g * H);
        #pragma unroll
        for (int k = 0; k < H / 4; k++) {
            float4 v = wv[k];
            whh[4*k+0] = v.x; whh[4*k+1] = v.y; whh[4*k+2] = v.z; whh[4*k+3] = v.w;
        }
    }

    __shared__ __align__(16) float gbuf[64 * 256];   // 64 KB: G1 chunk
    __shared__ __align__(16) float h_s[H];
    __shared__ __align__(16) float c_s[H];
    __shared__ float gates[256];
    __shared__ __align__(16) float xs[2*H];
    __shared__ __align__(16) float yvec[2*H];

    if (g < H) { h_s[g] = 0.0f; c_s[g] = 0.0f; }

    const float4* G14 = (const float4*)G1;
    for (int s = 0; s < L; s++) {
        if ((s & 63) == 0) {
            const int V = min(64, L - s);
            float4* gb4 = (float4*)gbuf;
            const float4* src = G14 + ((size_t)b * TMAX + s) * 64;
            for (int i = g; i < V * 64; i += 256) gb4[i] = src[i];
            __syncthreads();
        }
        float a0 = gbuf[(s & 63) * 256 + g], a1 = 0.0f, a2 = 0.0f, a3 = 0.0f;
        const float4* h4 = (const float4*)h_s;
        #pragma unroll
        for (int k = 0; k < H / 4; k++) {
            float4 hv = h4[k];
            a0 = fmaf(whh[4*k+0], hv.x, a0);
            a1 = fmaf(whh[4*k+1], hv.y, a1);
            a2 = fmaf(whh[4*k+2], hv.z, a2);
            a3 = fmaf(whh[4*k+3], hv.w, a3);
        }
        const float acc = (a0 + a1) + (a2 + a3);
        gates[g] = (g >= 128 && g < 192) ? tanhf_(acc) : sigmoidf_(acc);
        __syncthreads();
        if (g < H) {
            const float ig = gates[g], fg = gates[H + g];
            const float gg = gates[2*H + g], og = gates[3*H + g];
            const float c = fmaf(fg, c_s[g], ig * gg);
            c_s[g] = c;
            h_s[g] = og * tanhf_(c);
        }
        __syncthreads();
    }

    // epilogue: yvec = [h1f_last, h1b_first(zero-state => no W_hh term)]
    if (g < H) yvec[g] = h_s[g];
    if (g < 2*H) xs[g] = h0[((size_t)b * TMAX + (L - 1)) * (2*H) + g];
    __syncthreads();

    float ab0 = bih_b[g] + bhh_b[g], ab1 = 0.0f, ab2 = 0.0f, ab3 = 0.0f;
    {
        const float4* wb4 = (const float4*)(Wih_b + (size_t)g * (2*H));
        const float4* xv4 = (const float4*)xs;
        #pragma unroll
        for (int k = 0; k < (2*H) / 4; k++) {
            float4 wv = wb4[k]; float4 xv = xv4[k];
            ab0 = fmaf(wv.x, xv.x, ab0); ab1 = fmaf(wv.y, xv.y, ab1);
            ab2 = fmaf(wv.z, xv.z, ab2); ab3 = fmaf(wv.w, xv.w, ab3);
        }
    }
    const float accb = (ab0 + ab1) + (ab2 + ab3);
    gates[g] = (g >= 128 && g < 192) ? tanhf_(accb) : sigmoidf_(accb);
    __syncthreads();
    if (g < H) {
        const float ig = gates[g];
        const float gg = gates[2*H + g], og = gates[3*H + g];
        yvec[H + g] = og * tanhf_(ig * gg);
    }
    __syncthreads();

    const float4* yv = (const float4*)yvec;
    for (int o = g; o < NC; o += 256) {
        float acc2 = bout[o];
        const float4* wr = (const float4*)(Wout + (size_t)o * (2*H));
        #pragma unroll
        for (int k = 0; k < (2*H) / 4; k++) {
            float4 w2 = wr[k]; float4 yy = yv[k];
            acc2 = fmaf(w2.x, yy.x, acc2);
            acc2 = fmaf(w2.y, yy.y, acc2);
            acc2 = fmaf(w2.z, yy.z, acc2);
            acc2 = fmaf(w2.w, yy.w, acc2);
        }
        out[(size_t)b * NC + o] = acc2;
    }
}

// ---------------- Fallback (ws too small for G1): fused xW in-step ----------
// Same as rec kernel but computes xW from an LDS-staged h0 chunk per step.
__global__ __launch_bounds__(256) void lstm_layer1_fused(
    const float* __restrict__ h0, const int* __restrict__ lengths,
    const float* __restrict__ Wih_f, const float* __restrict__ Whh_f,
    const float* __restrict__ bih_f, const float* __restrict__ bhh_f,
    const float* __restrict__ Wih_b,
    const float* __restrict__ bih_b, const float* __restrict__ bhh_b,
    const float* __restrict__ Wout, const float* __restrict__ bout,
    float* __restrict__ out)
{
    const int b = blockIdx.x;
    const int g = threadIdx.x;
    const int L = lengths[b];

    float wih[2*H];
    {
        const float4* wv = (const float4*)(Wih_f + g * (2*H));
        #pragma unroll
        for (int k = 0; k < (2*H) / 4; k++) {
            float4 v = wv[k];
            wih[4*k+0] = v.x; wih[4*k+1] = v.y; wih[4*k+2] = v.z; wih[4*k+3] = v.w;
        }
    }
    float whh[H];
    {
        const float4* wv = (const float4*)(Whh_f + g * H);
        #pragma unroll
        for (int k = 0; k < H / 4; k++) {
            float4 v = wv[k];
            whh[4*k+0] = v.x; whh[4*k+1] = v.y; whh[4*k+2] = v.z; whh[4*k+3] = v.w;
        }
    }
    const float bias = bih_f[g] + bhh_f[g];

    __shared__ __align__(16) float4 xb4[64 * 32];    // 32 KB: h0 chunk
    __shared__ __align__(16) float h_s[H];
    __shared__ __align__(16) float c_s[H];
    __shared__ float gates[256];
    __shared__ __align__(16) float xs[2*H];
    __shared__ __align__(16) float yvec[2*H];

    if (g < H) { h_s[g] = 0.0f; c_s[g] = 0.0f; }

    for (int s = 0; s < L; s++) {
        if ((s & 63) == 0) {
            const int V = min(64, L - s);
            const float4* src = (const float4*)h0 + ((size_t)b * TMAX + s) * 32;
            for (int i = g; i < V * 32; i += 256) xb4[i] = src[i];
            __syncthreads();
        }
        const float4* xr = xb4 + (s & 63) * 32;
        float a0 = bias, a1 = 0.0f, a2 = 0.0f, a3 = 0.0f;
        #pragma unroll
        for (int k = 0; k < 32; k++) {
            float4 v = xr[k];
            a0 = fmaf(wih[4*k+0], v.x, a0);
            a1 = fmaf(wih[4*k+1], v.y, a1);
            a2 = fmaf(wih[4*k+2], v.z, a2);
            a3 = fmaf(wih[4*k+3], v.w, a3);
        }
        const float4* h4 = (const float4*)h_s;
        #pragma unroll
        for (int k = 0; k < H / 4; k++) {
            float4 hv = h4[k];
            a0 = fmaf(whh[4*k+0], hv.x, a0);
            a1 = fmaf(whh[4*k+1], hv.y, a1);
            a2 = fmaf(whh[4*k+2], hv.z, a2);
            a3 = fmaf(whh[4*k+3], hv.w, a3);
        }
        const float acc = (a0 + a1) + (a2 + a3);
        gates[g] = (g >= 128 && g < 192) ? tanhf_(acc) : sigmoidf_(acc);
        __syncthreads();
        if (g < H) {
            const float ig = gates[g], fg = gates[H + g];
            const float gg = gates[2*H + g], og = gates[3*H + g];
            const float c = fmaf(fg, c_s[g], ig * gg);
            c_s[g] = c;
            h_s[g] = og * tanhf_(c);
        }
        __syncthreads();
    }

    if (g < H) yvec[g] = h_s[g];
    if (g < 2*H) xs[g] = h0[((size_t)b * TMAX + (L - 1)) * (2*H) + g];
    __syncthreads();

    float ab0 = bih_b[g] + bhh_b[g], ab1 = 0.0f, ab2 = 0.0f, ab3 = 0.0f;
    {
        const float4* wb4 = (const float4*)(Wih_b + (size_t)g * (2*H));
        const float4* xv4 = (const float4*)xs;
        #pragma unroll
        for (int k = 0; k < (2*H) / 4; k++) {
            float4 wv = wb4[k]; float4 xv = xv4[k];
            ab0 = fmaf(wv.x, xv.x, ab0); ab1 = fmaf(wv.y, xv.y, ab1);
            ab2 = fmaf(wv.z, xv.z, ab2); ab3 = fmaf(wv.w, xv.w, ab3);
        }
    }
    const float accb = (ab0 + ab1) + (ab2 + ab3);
    gates[g] = (g >= 128 && g < 192) ? tanhf_(accb) : sigmoidf_(accb);
    __syncthreads();
    if (g < H) {
        const float ig = gates[g];
        const float gg = gates[2*H + g], og = gates[3*H + g];
        yvec[H + g] = og * tanhf_(ig * gg);
    }
    __syncthreads();

    const float4* yv = (const float4*)yvec;
    for (int o = g; o < NC; o += 256) {
        float acc2 = bout[o];
        const float4* wr = (const float4*)(Wout + (size_t)o * (2*H));
        #pragma unroll
        for (int k = 0; k < (2*H) / 4; k++) {
            float4 w2 = wr[k]; float4 yy = yv[k];
            acc2 = fmaf(w2.x, yy.x, acc2);
            acc2 = fmaf(w2.y, yy.y, acc2);
            acc2 = fmaf(w2.z, yy.z, acc2);
            acc2 = fmaf(w2.w, yy.w, acc2);
        }
        out[(size_t)b * NC + o] = acc2;
    }
}

extern "C" void kernel_launch(void* const* d_in, const int* in_sizes, int n_in,
                              void* d_out, int out_size, void* d_ws, size_t ws_size,
                              hipStream_t stream) {
    const float* x        = (const float*)d_in[0];
    const int*   lengths  = (const int*)  d_in[1];
    const float* Wih_l0f  = (const float*)d_in[2];
    const float* Whh_l0f  = (const float*)d_in[3];
    const float* bih_l0f  = (const float*)d_in[4];
    const float* bhh_l0f  = (const float*)d_in[5];
    const float* Wih_l0b  = (const float*)d_in[6];
    const float* Whh_l0b  = (const float*)d_in[7];
    const float* bih_l0b  = (const float*)d_in[8];
    const float* bhh_l0b  = (const float*)d_in[9];
    const float* Wih_l1f  = (const float*)d_in[10];
    const float* Whh_l1f  = (const float*)d_in[11];
    const float* bih_l1f  = (const float*)d_in[12];
    const float* bhh_l1f  = (const float*)d_in[13];
    const float* Wih_l1b  = (const float*)d_in[14];
    // d_in[15] = Whh_l1b: unused (backward dir only needs its first step, h=0)
    const float* bih_l1b  = (const float*)d_in[16];
    const float* bhh_l1b  = (const float*)d_in[17];
    const float* Wout     = (const float*)d_in[18];
    const float* bout     = (const float*)d_in[19];
    float* out = (float*)d_out;

    float* h0 = (float*)d_ws;  // [B, T, 2H] = 256 MB
    const size_t h0_bytes = (size_t)BATCH * TMAX * (2*H) * sizeof(float);
    const size_t g1_bytes = (size_t)BATCH * TMAX * (4*H) * sizeof(float);

    lstm_layer0<<<dim3(BATCH, 2), 256, 0, stream>>>(
        x, lengths,
        Wih_l0f, Whh_l0f, bih_l0f, bhh_l0f,
        Wih_l0b, Whh_l0b, bih_l0b, bhh_l0b, h0);

    if (ws_size >= h0_bytes + g1_bytes) {
        float* G1 = (float*)((char*)d_ws + h0_bytes);  // [B, T, 4H] = 512 MB
        xw_gemm<<<dim3(TMAX / 64, BATCH), 256, 0, stream>>>(
            h0, lengths, Wih_l1f, bih_l1f, bhh_l1f, G1);
        lstm_layer1_rec<<<dim3(BATCH), 256, 0, stream>>>(
            G1, h0, lengths, Whh_l1f,
            Wih_l1b, bih_l1b, bhh_l1b, Wout, bout, out);
    } else {
        lstm_layer1_fused<<<dim3(BATCH), 256, 0, stream>>>(
            h0, lengths,
            Wih_l1f, Whh_l1f, bih_l1f, bhh_l1f,
            Wih_l1b, bih_l1b, bhh_l1b, Wout, bout, out);
    }
}